// Round 1
// baseline (23995.876 us; speedup 1.0000x reference)
//
#include <hip/hip_runtime.h>
#include <math.h>

#define NEGF (-1e9f)

static constexpr int kL = 12, kH = 12, kDK = 64, kDM = 768, kDFF = 3072, kV = 32128;
static constexpr int kB = 2, kS = 512, kT = 512;

// ---------------- reduction helpers (blocks of 256 threads = 4 waves) ----------------
__device__ __forceinline__ float blockSum(float v, float* red) {
#pragma unroll
  for (int o = 32; o > 0; o >>= 1) v += __shfl_down(v, o, 64);
  if ((threadIdx.x & 63) == 0) red[threadIdx.x >> 6] = v;
  __syncthreads();
  float r = red[0] + red[1] + red[2] + red[3];
  __syncthreads();
  return r;
}
__device__ __forceinline__ float blockMax(float v, float* red) {
#pragma unroll
  for (int o = 32; o > 0; o >>= 1) v = fmaxf(v, __shfl_down(v, o, 64));
  if ((threadIdx.x & 63) == 0) red[threadIdx.x >> 6] = v;
  __syncthreads();
  float r = fmaxf(fmaxf(red[0], red[1]), fmaxf(red[2], red[3]));
  __syncthreads();
  return r;
}

// ---------------- generic batched GEMM: C = op(A@B) [+ Ci] ----------------
// A: M x K (row-major, lda). B: K x N (ldb) or, if TRANSB, stored N x K (ldb).
// Batch via gridDim.z decomposed as (b, h) with independent strides.
// EPI: 0 = none, 1 = add Ci (ldci may be 0 for row-broadcast), 2 = relu.
// Requires M%64==0, N%64==0, K%16==0 (true for every shape in this model).
template <int TRANSB, int EPI>
__launch_bounds__(256)
__global__ void gemm64(const float* __restrict__ A, const float* __restrict__ Bm,
                       const float* __restrict__ Ci, float* __restrict__ C,
                       int M, int N, int K, int lda, int ldb, int ldc, int ldci,
                       int Hdim, long sAb, long sAh, long sBb, long sBh,
                       long sCb, long sCh, long sCib, long sCih) {
  const int z = blockIdx.z;
  const int bz = z / Hdim, hz = z % Hdim;
  A += bz * sAb + hz * sAh;
  Bm += bz * sBb + hz * sBh;
  C += bz * sCb + hz * sCh;
  if (EPI == 1) Ci += bz * sCib + hz * sCih;
  const int m0 = blockIdx.y * 64, n0 = blockIdx.x * 64;
  __shared__ float As[16][65];
  __shared__ float Bs[16][65];
  const int tid = threadIdx.x;
  const int tx = tid & 15, ty = tid >> 4;
  float acc[4][4] = {{0.f}};
  for (int k0 = 0; k0 < K; k0 += 16) {
    {
      const int kk = tid & 15, mm = tid >> 4;
#pragma unroll
      for (int r = 0; r < 4; ++r)
        As[kk][mm + 16 * r] = A[(long)(m0 + mm + 16 * r) * lda + (k0 + kk)];
    }
    if (TRANSB) {
      const int kk = tid & 15, nn = tid >> 4;
#pragma unroll
      for (int r = 0; r < 4; ++r)
        Bs[kk][nn + 16 * r] = Bm[(long)(n0 + nn + 16 * r) * ldb + (k0 + kk)];
    } else {
      const int nn = tid & 63, kk = tid >> 6;
#pragma unroll
      for (int r = 0; r < 4; ++r)
        Bs[kk + 4 * r][nn] = Bm[(long)(k0 + kk + 4 * r) * ldb + (n0 + nn)];
    }
    __syncthreads();
#pragma unroll
    for (int kk = 0; kk < 16; ++kk) {
      float av[4], bv[4];
#pragma unroll
      for (int i = 0; i < 4; ++i) av[i] = As[kk][ty * 4 + i];
#pragma unroll
      for (int j = 0; j < 4; ++j) bv[j] = Bs[kk][tx * 4 + j];
#pragma unroll
      for (int i = 0; i < 4; ++i)
#pragma unroll
        for (int j = 0; j < 4; ++j) acc[i][j] = fmaf(av[i], bv[j], acc[i][j]);
    }
    __syncthreads();
  }
#pragma unroll
  for (int i = 0; i < 4; ++i) {
    const long m = m0 + ty * 4 + i;
#pragma unroll
    for (int j = 0; j < 4; ++j) {
      const int n = n0 + tx * 4 + j;
      float v2 = acc[i][j];
      if (EPI == 1) v2 += Ci[m * (long)ldci + n];
      if (EPI == 2) v2 = fmaxf(v2, 0.f);
      C[m * (long)ldc + n] = v2;
    }
  }
}

// ---------------- small kernels ----------------
__global__ void k_embed(const float* __restrict__ emb, const int* __restrict__ tok,
                        float* __restrict__ dst) {
  const long row = blockIdx.x;
  const float* s = emb + (long)tok[row] * kDM;
  float* d = dst + row * kDM;
  for (int i = threadIdx.x; i < kDM; i += 256) d[i] = s[i];
}

__global__ void k_zero0(float* __restrict__ x, int n) {
  int i = blockIdx.x * 256 + threadIdx.x;
  if (i < n) x[(long)i * kDM] = 0.f;
}

__global__ void k_rms(const float* __restrict__ x, const float* __restrict__ g,
                      float* __restrict__ o, float scale) {
  __shared__ float red[4];
  const long row = blockIdx.x;
  const float* xr = x + row * kDM;
  float ss = 0.f;
  for (int i = threadIdx.x; i < kDM; i += 256) { float t = xr[i]; ss += t * t; }
  ss = blockSum(ss, red);
  const float inv = rsqrtf(ss * (1.f / kDM) + 1e-6f) * scale;
  float* orow = o + row * kDM;
  for (int i = threadIdx.x; i < kDM; i += 256) orow[i] = xr[i] * inv * g[i];
}

__global__ void k_softmax(float* __restrict__ p, int len) {
  __shared__ float red[4];
  const long row = blockIdx.x;
  float* pr = p + row * (long)len;
  float m = -3.4e38f;
  for (int i = threadIdx.x; i < len; i += 256) m = fmaxf(m, pr[i]);
  m = blockMax(m, red);
  float s = 0.f;
  for (int i = threadIdx.x; i < len; i += 256) { float e = expf(pr[i] - m); pr[i] = e; s += e; }
  s = blockSum(s, red);
  const float inv = 1.f / s;
  for (int i = threadIdx.x; i < len; i += 256) pr[i] *= inv;
}

// T5 relative-position buckets (f32 log order replicated from the reference)
__device__ __forceinline__ int bucket_bi(int q, int k) {
  int n = q - k;  // n = -(k-q)
  int ret = 0;
  if (n < 0) { ret = 16; n = -n; }
  if (n < 8) return ret + n;
  int lg = 8 + (int)(logf((float)n / 8.0f) / 2.772588722239781f * 8.0f);
  if (lg > 15) lg = 15;
  return ret + lg;
}
__device__ __forceinline__ int bucket_uni(int q, int k) {
  int n = q - k;
  if (n < 0) n = 0;
  if (n < 16) return n;
  int lg = 16 + (int)(logf((float)n / 16.0f) / 2.0794415416798357f * 16.0f);
  if (lg > 31) lg = 31;
  return lg;
}

__global__ void k_encbias(float* __restrict__ bias, const float* __restrict__ rb,
                          const int* __restrict__ slen) {
  long idx = (long)blockIdx.x * 256 + threadIdx.x;
  const long total = (long)kB * kH * kS * kS;
  if (idx >= total) return;
  int kpos = idx % kS;
  int qpos = (idx / kS) % kS;
  int hh = (idx / ((long)kS * kS)) % kH;
  int bb = idx / ((long)kH * kS * kS);
  float v = rb[bucket_bi(qpos, kpos) * kH + hh];
  if (kpos >= slen[bb]) v += NEGF;
  bias[idx] = v;
}

__global__ void k_biasupd(float* __restrict__ bias, const float* __restrict__ pm) {
  long idx = (long)blockIdx.x * 256 + threadIdx.x;
  const long total = (long)kB * kH * kS * kS;
  if (idx >= total) return;
  int kpos = idx % kS;
  int qpos = (idx / kS) % kS;
  int bb = idx / ((long)kH * kS * kS);
  float v = bias[idx] + pm[bb * kS + kpos] + pm[bb * kS + qpos];
  bias[idx] = (qpos == kpos) ? 0.f : v;
}

__global__ void k_prune(const float* __restrict__ x, const float* __restrict__ gum,
                        const int* __restrict__ slen, const int* __restrict__ keep,
                        float* __restrict__ pmp, float* __restrict__ pmask,
                        float* __restrict__ pprob, int layer) {
  int i = blockIdx.x * 256 + threadIdx.x;
  if (i >= kB * kS) return;
  int bb = i / kS, s = i % kS;
  float z = (x[(long)i * kDM] + gum[((long)bb * kL + layer) * kS + s] + 3.0f) * 2.0f;
  float pm = (z >= 0.f) ? (-log1pf(expf(-z))) : (z - log1pf(expf(z)));  // log_sigmoid(z)
  if (layer > 0) pm += pmp[i];
  if (s == keep[bb]) pm = 0.f;
  pmp[i] = pm;
  const long oidx = ((long)bb * kL + layer) * kS + s;
  pmask[oidx] = pm;
  pprob[oidx] = expf(pm * 0.125f) * ((s < slen[bb]) ? 1.f : 0.f);
}

__global__ void k_crossvec(const int* __restrict__ slen, const float* __restrict__ pmask,
                           float* __restrict__ cv) {
  int i = blockIdx.x * 256 + threadIdx.x;
  if (i >= kB * kS) return;
  int bb = i / kS, s = i % kS;
  cv[i] = ((s < slen[bb]) ? 0.f : NEGF) + pmask[((long)bb * kL + (kL - 1)) * kS + s];
}

__global__ void k_decbias(float* __restrict__ bias, const float* __restrict__ rb,
                          const int* __restrict__ slen, const int* __restrict__ tlen) {
  long idx = (long)blockIdx.x * 256 + threadIdx.x;
  const long total = (long)kB * kH * kT * kT;
  if (idx >= total) return;
  int kpos = idx % kT;
  int tpos = (idx / kT) % kT;
  int hh = (idx / ((long)kT * kT)) % kH;
  int bb = idx / ((long)kH * kT * kT);
  float v = rb[bucket_uni(tpos, kpos) * kH + hh];
  float tm;
  if (kpos == 0 && tpos >= tlen[bb]) {
    tm = 0.f;  // col-0 unblock past tgt length
  } else {
    float tp = (kpos < slen[bb]) ? 0.f : NEGF;  // note: uses src_lengths (per reference)
    bool win = (kpos <= tpos) && (kpos >= tpos - 128);
    tm = tp + (win ? 0.f : NEGF);
  }
  bias[idx] = v + tm;
}

// ---------------- host-side GEMM dispatch ----------------
static void gemm(hipStream_t st, int transB, int epi,
                 const float* A, const float* Bm, const float* Ci, float* C,
                 int M, int N, int K, int lda, int ldb, int ldc, int ldci,
                 int Z, int Hdim,
                 long sAb, long sAh, long sBb, long sBh,
                 long sCb, long sCh, long sCib, long sCih) {
  dim3 g(N / 64, M / 64, Z), blk(256, 1, 1);
#define GL(TB, EP) gemm64<TB, EP><<<g, blk, 0, st>>>(A, Bm, Ci, C, M, N, K, lda, ldb, ldc, ldci, \
                                                     Hdim, sAb, sAh, sBb, sBh, sCb, sCh, sCib, sCih)
  if (transB) {
    if (epi == 1) GL(1, 1);
    else          GL(1, 0);
  } else {
    if (epi == 1)      GL(0, 1);
    else if (epi == 2) GL(0, 2);
    else               GL(0, 0);
  }
#undef GL
}
static void gemm1(hipStream_t st, int transB, int epi, const float* A, const float* Bm,
                  const float* Ci, float* C, int M, int N, int K, int lda, int ldb, int ldc,
                  int ldci) {
  gemm(st, transB, epi, A, Bm, Ci, C, M, N, K, lda, ldb, ldc, ldci, 1, 1, 0, 0, 0, 0, 0, 0, 0, 0);
}

extern "C" void kernel_launch(void* const* d_in, const int* in_sizes, int n_in,
                              void* d_out, int out_size, void* d_ws, size_t ws_size,
                              hipStream_t stream) {
  (void)in_sizes; (void)n_in; (void)out_size; (void)ws_size;
  const float* embed   = (const float*)d_in[0];
  const float* enc_lnw = (const float*)d_in[1];
  const float* enc_aw  = (const float*)d_in[2];
  const float* enc_wi  = (const float*)d_in[3];
  const float* enc_wo  = (const float*)d_in[4];
  const float* enc_rb  = (const float*)d_in[5];
  const float* enc_fln = (const float*)d_in[6];
  const float* dec_lnw = (const float*)d_in[7];
  const float* dec_sw  = (const float*)d_in[8];
  const float* dec_cw  = (const float*)d_in[9];
  const float* dec_wi  = (const float*)d_in[10];
  const float* dec_wo  = (const float*)d_in[11];
  const float* dec_rb  = (const float*)d_in[12];
  const float* dec_fln = (const float*)d_in[13];
  const float* gum     = (const float*)d_in[14];
  const int* s_tok = (const int*)d_in[15];
  const int* s_len = (const int*)d_in[16];
  const int* t_tok = (const int*)d_in[17];
  const int* t_len = (const int*)d_in[18];
  const int* keep  = (const int*)d_in[19];

  float* outp  = (float*)d_out;
  float* memo  = outp;                                // [B,S,DM]
  float* pmask = outp + (long)kB * kS * kDM;          // [B,L,S]
  float* pprob = pmask + (long)kB * kL * kS;          // [B,L,S]
  float* logit = pprob + (long)kB * kL * kS;          // [B,T,V]

  float* w = (float*)d_ws;
  const long NX = (long)kB * kS * kDM;
  float* x  = w;            // hidden stream (enc x, then dec y)
  float* hn = x + NX;       // normed
  float* qb = hn + NX;
  float* kb = qb + NX;
  float* vb = kb + NX;
  float* ob = vb + NX;
  float* sc = ob + NX;                          // scores [B,H,512,512]; aliases FFN-mid
  float* ffm = sc;                              // [B*S, DFF] (3.1M floats <= 6.3M)
  float* bias = sc + (long)kB * kH * kS * kS;   // [B,H,512,512]
  float* pmp = bias + (long)kB * kH * kS * kS;  // [B,S]
  float* crb = pmp + kB * kS;                   // [B,S]

  const long SD = (long)kS * kDM;      // per-batch hidden stride
  const long SS = (long)kS * kS;       // per-head score stride
  const long HSS = (long)kH * SS;

  // ---------------- encoder ----------------
  k_encbias<<<(kB * kH * kS * kS + 255) / 256, 256, 0, stream>>>(bias, enc_rb, s_len);
  k_embed<<<kB * kS, 256, 0, stream>>>(embed, s_tok, x);

  for (int i = 0; i < kL; ++i) {
    const float* wl = enc_aw + (long)i * 4 * kDM * kDM;
    k_zero0<<<(kB * kS + 255) / 256, 256, 0, stream>>>(x, kB * kS);
    k_rms<<<kB * kS, 256, 0, stream>>>(x, enc_lnw + (long)i * 2 * kDM, hn, 1.0f);
    gemm1(stream, 0, 0, hn, wl + 0L * kDM * kDM, nullptr, qb, kB * kS, kDM, kDM, kDM, kDM, kDM, 0);
    gemm1(stream, 0, 0, hn, wl + 1L * kDM * kDM, nullptr, kb, kB * kS, kDM, kDM, kDM, kDM, kDM, 0);
    gemm1(stream, 0, 0, hn, wl + 2L * kDM * kDM, nullptr, vb, kB * kS, kDM, kDM, kDM, kDM, kDM, 0);
    // scores[b,h] = q @ k^T + bias
    gemm(stream, 1, 1, qb, kb, bias, sc, kS, kS, kDK, kDM, kDM, kS, kS,
         kB * kH, kH, SD, 64, SD, 64, HSS, SS, HSS, SS);
    k_softmax<<<kB * kH * kS, 256, 0, stream>>>(sc, kS);
    gemm(stream, 0, 0, sc, vb, nullptr, ob, kS, kDK, kS, kS, kDM, kDM, 0,
         kB * kH, kH, HSS, SS, SD, 64, SD, 64, 0, 0);
    gemm1(stream, 0, 1, ob, wl + 3L * kDM * kDM, x, x, kB * kS, kDM, kDM, kDM, kDM, kDM, kDM);
    k_rms<<<kB * kS, 256, 0, stream>>>(x, enc_lnw + (long)i * 2 * kDM + kDM, hn, 1.0f);
    gemm1(stream, 0, 2, hn, enc_wi + (long)i * kDM * kDFF, nullptr, ffm, kB * kS, kDFF, kDM, kDM, kDFF, kDFF, 0);
    gemm1(stream, 0, 1, ffm, enc_wo + (long)i * kDFF * kDM, x, x, kB * kS, kDM, kDFF, kDFF, kDM, kDM, kDM);
    k_prune<<<(kB * kS + 255) / 256, 256, 0, stream>>>(x, gum, s_len, keep, pmp, pmask, pprob, i);
    if (i + 1 < kL)
      k_biasupd<<<(kB * kH * kS * kS + 255) / 256, 256, 0, stream>>>(bias, pmp);
  }
  k_rms<<<kB * kS, 256, 0, stream>>>(x, enc_fln, memo, 1.0f);

  // ---------------- decoder ----------------
  k_crossvec<<<(kB * kS + 255) / 256, 256, 0, stream>>>(s_len, pmask, crb);
  k_decbias<<<(kB * kH * kT * kT + 255) / 256, 256, 0, stream>>>(bias, dec_rb, s_len, t_len);
  k_embed<<<kB * kT, 256, 0, stream>>>(embed, t_tok, x);

  const long TD = (long)kT * kDM;
  const long TT = (long)kT * kT;
  const long HTT = (long)kH * TT;
  const long TS = (long)kT * kS;
  const long HTS = (long)kH * TS;

  for (int i = 0; i < kL; ++i) {
    const float* wsl = dec_sw + (long)i * 4 * kDM * kDM;
    const float* wcl = dec_cw + (long)i * 4 * kDM * kDM;
    // self-attn
    k_rms<<<kB * kT, 256, 0, stream>>>(x, dec_lnw + (long)i * 3 * kDM, hn, 1.0f);
    gemm1(stream, 0, 0, hn, wsl + 0L * kDM * kDM, nullptr, qb, kB * kT, kDM, kDM, kDM, kDM, kDM, 0);
    gemm1(stream, 0, 0, hn, wsl + 1L * kDM * kDM, nullptr, kb, kB * kT, kDM, kDM, kDM, kDM, kDM, 0);
    gemm1(stream, 0, 0, hn, wsl + 2L * kDM * kDM, nullptr, vb, kB * kT, kDM, kDM, kDM, kDM, kDM, 0);
    gemm(stream, 1, 1, qb, kb, bias, sc, kT, kT, kDK, kDM, kDM, kT, kT,
         kB * kH, kH, TD, 64, TD, 64, HTT, TT, HTT, TT);
    k_softmax<<<kB * kH * kT, 256, 0, stream>>>(sc, kT);
    gemm(stream, 0, 0, sc, vb, nullptr, ob, kT, kDK, kT, kT, kDM, kDM, 0,
         kB * kH, kH, HTT, TT, TD, 64, TD, 64, 0, 0);
    gemm1(stream, 0, 1, ob, wsl + 3L * kDM * kDM, x, x, kB * kT, kDM, kDM, kDM, kDM, kDM, kDM);
    // cross-attn (K/V from mem)
    k_rms<<<kB * kT, 256, 0, stream>>>(x, dec_lnw + (long)i * 3 * kDM + kDM, hn, 1.0f);
    gemm1(stream, 0, 0, hn, wcl + 0L * kDM * kDM, nullptr, qb, kB * kT, kDM, kDM, kDM, kDM, kDM, 0);
    gemm1(stream, 0, 0, memo, wcl + 1L * kDM * kDM, nullptr, kb, kB * kS, kDM, kDM, kDM, kDM, kDM, 0);
    gemm1(stream, 0, 0, memo, wcl + 2L * kDM * kDM, nullptr, vb, kB * kS, kDM, kDM, kDM, kDM, kDM, 0);
    gemm(stream, 1, 1, qb, kb, crb, sc, kT, kS, kDK, kDM, kDM, kS, 0,
         kB * kH, kH, TD, 64, SD, 64, HTS, TS, (long)kS, 0);
    k_softmax<<<kB * kH * kT, 256, 0, stream>>>(sc, kS);
    gemm(stream, 0, 0, sc, vb, nullptr, ob, kT, kDK, kS, kS, kDM, kDM, 0,
         kB * kH, kH, HTS, TS, SD, 64, TD, 64, 0, 0);
    gemm1(stream, 0, 1, ob, wcl + 3L * kDM * kDM, x, x, kB * kT, kDM, kDM, kDM, kDM, kDM, kDM);
    // ffn
    k_rms<<<kB * kT, 256, 0, stream>>>(x, dec_lnw + (long)i * 3 * kDM + 2 * kDM, hn, 1.0f);
    gemm1(stream, 0, 2, hn, dec_wi + (long)i * kDM * kDFF, nullptr, ffm, kB * kT, kDFF, kDM, kDM, kDFF, kDFF, 0);
    gemm1(stream, 0, 1, ffm, dec_wo + (long)i * kDFF * kDM, x, x, kB * kT, kDM, kDFF, kDFF, kDM, kDM, kDM);
  }
  // final LN * DM^-0.5, then logits = y @ embed^T
  k_rms<<<kB * kT, 256, 0, stream>>>(x, dec_fln, hn, 0.036084391824351615f);
  gemm1(stream, 1, 0, hn, embed, nullptr, logit, kB * kT, kV, kDM, kDM, kDM, kV, 0);
}